// Round 9
// baseline (2452.945 us; speedup 1.0000x reference)
//
#include <hip/hip_runtime.h>
#include <stdint.h>

using half8 = __attribute__((ext_vector_type(8))) _Float16;
using half4 = __attribute__((ext_vector_type(4))) _Float16;
using f32x4 = __attribute__((ext_vector_type(4))) float;

#define BM 256
#define BN 128
#define BK 32

// Bank-conflict-free layout: granule (row, k8) at byte row*64 + (k8 ^ ((row>>1)&3))*16.
// Read side uses swz() (16-row column reads -> 2-way aliasing = free);
// GLD staging realizes it via pre-swizzled global source addresses
// (LDS dest must be linear: wave-uniform base + lane*16).
__device__ __forceinline__ int swz(int row, int kb) {
  return (row << 6) + ((((kb >> 4) ^ ((row >> 1) & 3)) << 4) | (kb & 15));
}

#define GLD(src, dst)                                                          \
  __builtin_amdgcn_global_load_lds(                                            \
      (const __attribute__((address_space(1))) void*)(src),                    \
      (__attribute__((address_space(3))) void*)(dst), 16, 0, 0)

// ---------------- L1/L3 kernel (r7-proven): tri-buffer counted-vmcnt --------
// MODE 0: hi/lo inputs -> Chi+Clo (split-f16 precise, 3 MFMA/frag).
// MODE 2: hi-only inputs -> f32 C.
template <int MODE>
__global__ __launch_bounds__(1024, 4)
void gemm_tri(const _Float16* __restrict__ Ahi, const _Float16* __restrict__ Alo,
              const _Float16* __restrict__ Bhi, const _Float16* __restrict__ Blo,
              const float* __restrict__ bias,
              _Float16* __restrict__ Chi, _Float16* __restrict__ Clo,
              float* __restrict__ Cf, int M, int N, int K) {
  constexpr bool LO = (MODE < 2);
  constexpr int AHI = 0;
  constexpr int ALO = 16384;
  constexpr int BHI = LO ? 32768 : 16384;
  constexpr int BLO = 40960;
  constexpr int STG = LO ? 49152 : 24576;
  __shared__ char lds[3 * STG];

  const int tid = threadIdx.x;
  const int m0 = blockIdx.y * BM;
  const int n0 = blockIdx.x * BN;
  const int wave = tid >> 6, lane = tid & 63;
  const int wm = wave >> 1, wn = wave & 1;   // 8x2 wave grid; wave tile 32x64
  const int NK = K / BK;

  f32x4 acc_hi[2][4], acc_mid[2][4];
#pragma unroll
  for (int m = 0; m < 2; m++)
#pragma unroll
    for (int n = 0; n < 4; n++) { acc_hi[m][n] = (f32x4)0.0f; acc_mid[m][n] = (f32x4)0.0f; }

  const int srow = tid >> 2;                  // 0..255 (A rows)
  const int kx = (tid & 3) ^ ((srow >> 1) & 3);
  const size_t aoff = (size_t)(m0 + srow) * K + kx * 8;
  const int brow = (tid & 511) >> 2;          // 0..127 (B rows)
  const size_t boff = (size_t)(n0 + brow) * K + kx * 8;

  auto STAGE = [&](int buf, int ks) {
    char* sb = lds + buf * STG;
    const size_t ko = (size_t)ks * BK;
    GLD(Ahi + aoff + ko, sb + AHI + (wave << 10));
    if constexpr (LO) {
      GLD(Alo + aoff + ko, sb + ALO + (wave << 10));
      if (wave < 8) GLD(Bhi + boff + ko, sb + BHI + (wave << 10));
      else          GLD(Blo + boff + ko, sb + BLO + ((wave - 8) << 10));
    } else {
      if (wave < 8) GLD(Bhi + boff + ko, sb + BHI + (wave << 10));
    }
  };

  auto COMPUTE = [&](int buf) {
    char* base = lds + buf * STG;
    const int kb = (lane >> 4) << 4;
    const int rl = lane & 15;
    half8 ah[2], al[2], bh[4], bl[4];
#pragma unroll
    for (int mi = 0; mi < 2; mi++) {
      int off = swz(wm * 32 + mi * 16 + rl, kb);
      ah[mi] = *(half8*)(base + AHI + off);
      if constexpr (LO) al[mi] = *(half8*)(base + ALO + off);
    }
#pragma unroll
    for (int ni = 0; ni < 4; ni++) {
      int off = swz(wn * 64 + ni * 16 + rl, kb);
      bh[ni] = *(half8*)(base + BHI + off);
      if constexpr (LO) bl[ni] = *(half8*)(base + BLO + off);
    }
    __builtin_amdgcn_s_setprio(1);
#pragma unroll
    for (int mi = 0; mi < 2; mi++)
#pragma unroll
      for (int ni = 0; ni < 4; ni++) {
        acc_hi[mi][ni] = __builtin_amdgcn_mfma_f32_16x16x32_f16(ah[mi], bh[ni], acc_hi[mi][ni], 0, 0, 0);
        if constexpr (LO) {
          acc_mid[mi][ni] = __builtin_amdgcn_mfma_f32_16x16x32_f16(ah[mi], bl[ni], acc_mid[mi][ni], 0, 0, 0);
          acc_mid[mi][ni] = __builtin_amdgcn_mfma_f32_16x16x32_f16(al[mi], bh[ni], acc_mid[mi][ni], 0, 0, 0);
        }
      }
    __builtin_amdgcn_s_setprio(0);
  };

  STAGE(0, 0);
  STAGE(1, 1);
  int cur = 0;
  for (int ks = 0; ks < NK; ++ks) {
    if (ks + 1 < NK) {
      if constexpr (LO) {
        asm volatile("s_waitcnt vmcnt(3)" ::: "memory");
      } else {
        if (wave < 8) asm volatile("s_waitcnt vmcnt(2)" ::: "memory");
        else          asm volatile("s_waitcnt vmcnt(1)" ::: "memory");
      }
    } else {
      asm volatile("s_waitcnt vmcnt(0)" ::: "memory");
    }
    __builtin_amdgcn_s_barrier();
    if (ks + 2 < NK) {
      int nbuf = cur + 2; if (nbuf >= 3) nbuf -= 3;
      STAGE(nbuf, ks + 2);
    }
    COMPUTE(cur);
    if (++cur == 3) cur = 0;
  }

  const int col_l = lane & 15, rgrp = lane >> 4;
#pragma unroll
  for (int ni = 0; ni < 4; ni++) {
    int col = n0 + wn * 64 + ni * 16 + col_l;
    float bv = bias[col];
#pragma unroll
    for (int mi = 0; mi < 2; mi++) {
      int rowb = m0 + wm * 32 + mi * 16 + rgrp * 4;
#pragma unroll
      for (int i = 0; i < 4; i++) {
        size_t idx = (size_t)(rowb + i) * N + col;
        if constexpr (MODE == 2) {
          Cf[idx] = acc_hi[mi][ni][i] + bv;
        } else {
          float c = acc_hi[mi][ni][i] + acc_mid[mi][ni][i] * (1.0f / 2048.0f) + bv;
          _Float16 hh = (_Float16)c;
          Chi[idx] = hh;
          if constexpr (MODE == 0) Clo[idx] = (_Float16)((c - (float)hh) * 2048.0f);
        }
      }
    }
  }
}

// ---------------- L2 kernel: hi-only f16, 256x256 tile, 64x64 wave tiles ----
// 16 waves (4/SIMD), tri-buffer, counted vmcnt(2). acc 64 AGPR + ~50 VGPR
// fits the 128-unified budget at 4 waves/SIMD. Masks made exact downstream
// by sda_fix's fp64 recheck with TAU=5e-3 (hi-only GEMM max err ~1.6e-3).
#define SQ_STG 32768

__global__ __launch_bounds__(1024, 4)
void gemm_sq(const _Float16* __restrict__ Ahi, const _Float16* __restrict__ Bhi,
             const float* __restrict__ bias, _Float16* __restrict__ Chi,
             int M, int N, int K) {
  __shared__ char lds[3 * SQ_STG];
  const int tid = threadIdx.x;
  const int m0 = blockIdx.y * 256;
  const int n0 = blockIdx.x * 256;
  const int wave = tid >> 6, lane = tid & 63;
  const int wm = wave >> 2, wn = wave & 3;   // 4x4 wave grid; wave tile 64x64
  const int NK = K / BK;

  f32x4 acc[4][4];
#pragma unroll
  for (int m = 0; m < 4; m++)
#pragma unroll
    for (int n = 0; n < 4; n++) acc[m][n] = (f32x4)0.0f;

  const int srow = tid >> 2;                  // 0..255
  const int kx = (tid & 3) ^ ((srow >> 1) & 3);
  const size_t aoff = (size_t)(m0 + srow) * K + kx * 8;
  const size_t boff = (size_t)(n0 + srow) * K + kx * 8;

  // Loop-invariant swizzled fragment offsets (saves per-iter VALU + regs).
  const int kb = (lane >> 4) << 4;
  const int rl = lane & 15;
  int aswz[4], bswz[4];
#pragma unroll
  for (int i = 0; i < 4; i++) {
    aswz[i] = swz(wm * 64 + i * 16 + rl, kb);
    bswz[i] = 16384 + swz(wn * 64 + i * 16 + rl, kb);
  }

  auto STAGE = [&](int buf, int ks) {
    char* sb = lds + buf * SQ_STG + (wave << 10);
    const size_t ko = (size_t)ks * BK;
    GLD(Ahi + aoff + ko, sb);
    GLD(Bhi + boff + ko, sb + 16384);
  };

  auto COMPUTE = [&](int buf) {
    char* base = lds + buf * SQ_STG;
    half8 ah[4], bh[4];
#pragma unroll
    for (int i = 0; i < 4; i++) {
      ah[i] = *(half8*)(base + aswz[i]);
      bh[i] = *(half8*)(base + bswz[i]);
    }
    __builtin_amdgcn_s_setprio(1);
#pragma unroll
    for (int mi = 0; mi < 4; mi++)
#pragma unroll
      for (int ni = 0; ni < 4; ni++)
        acc[mi][ni] = __builtin_amdgcn_mfma_f32_16x16x32_f16(ah[mi], bh[ni], acc[mi][ni], 0, 0, 0);
    __builtin_amdgcn_s_setprio(0);
  };

  STAGE(0, 0);
  STAGE(1, 1);
  int cur = 0;
  for (int ks = 0; ks < NK; ++ks) {
    if (ks + 1 < NK) asm volatile("s_waitcnt vmcnt(2)" ::: "memory");
    else             asm volatile("s_waitcnt vmcnt(0)" ::: "memory");
    __builtin_amdgcn_s_barrier();
    if (ks + 2 < NK) {
      int nbuf = cur + 2; if (nbuf >= 3) nbuf -= 3;
      STAGE(nbuf, ks + 2);
    }
    COMPUTE(cur);
    if (++cur == 3) cur = 0;
  }

  const int col_l = lane & 15, rgrp = lane >> 4;
#pragma unroll
  for (int ni = 0; ni < 4; ni++) {
    int col = n0 + wn * 64 + ni * 16 + col_l;
    float bv = bias[col];
#pragma unroll
    for (int mi = 0; mi < 4; mi++) {
      int rowb = m0 + wm * 64 + mi * 16 + rgrp * 4;
#pragma unroll
      for (int i = 0; i < 4; i++)
        Chi[(size_t)(rowb + i) * N + col] = (_Float16)(acc[mi][ni][i] + bv);
    }
  }
}

// Split f32 -> (hi f16, lo f16 scaled by 2048). Xlo may be null (hi-only).
__global__ __launch_bounds__(256)
void split_kernel(const float* __restrict__ X, _Float16* __restrict__ Xhi,
                  _Float16* __restrict__ Xlo, size_t n4) {
  size_t i = (size_t)blockIdx.x * 256 + threadIdx.x;
  const size_t stride = (size_t)gridDim.x * 256;
  for (; i < n4; i += stride) {
    float4 q = ((const float4*)X)[i];
    float a[4] = {q.x, q.y, q.z, q.w};
    half4 h, l;
#pragma unroll
    for (int j = 0; j < 4; ++j) {
      _Float16 hh = (_Float16)a[j];
      h[j] = hh;
      l[j] = (_Float16)((a[j] - (float)hh) * 2048.0f);
    }
    ((half4*)Xhi)[i] = h;
    if (Xlo) ((half4*)Xlo)[i] = l;
  }
}

// One block per row of Z (hi/lo f16 repr; Zlo may be null):
//  1) reconstruct row; flag |z| < TAU; recompute flagged cols in fp64 from the
//     f32 activation path (Af) or reconstructed hi/lo activations (true sign)
//  2) first all-pos / all-neg group on corrected values
//  3) write back changed elements (group scale/zero + borderline patches)
__global__ __launch_bounds__(256)
void sda_fix(_Float16* __restrict__ Zhi, _Float16* __restrict__ Zlo,
             const float* __restrict__ Af,
             const _Float16* __restrict__ Ahi, const _Float16* __restrict__ Alo,
             const float* __restrict__ W, const float* __restrict__ bias,
             int H, int K, float TAU) {
  __shared__ int sPos[4], sNeg[4];
  __shared__ int nFix;
  __shared__ int fixIdx[96];
  __shared__ double sRed[4];
  __shared__ float sVal;
  const int row = blockIdx.x;
  _Float16* zh = Zhi + (size_t)row * H;
  _Float16* zl = Zlo ? Zlo + (size_t)row * H : nullptr;
  const int t = threadIdx.x;

  if (t == 0) nFix = 0;
  __syncthreads();

  float v[16];
  {
    half8 a0 = ((const half8*)zh)[t * 2], a1 = ((const half8*)zh)[t * 2 + 1];
    if (zl) {
      half8 b0 = ((const half8*)zl)[t * 2], b1 = ((const half8*)zl)[t * 2 + 1];
#pragma unroll
      for (int e = 0; e < 8; ++e) {
        v[e]     = (float)a0[e] + (float)b0[e] * (1.0f / 2048.0f);
        v[8 + e] = (float)a1[e] + (float)b1[e] * (1.0f / 2048.0f);
      }
    } else {
#pragma unroll
      for (int e = 0; e < 8; ++e) { v[e] = (float)a0[e]; v[8 + e] = (float)a1[e]; }
    }
  }
#pragma unroll
  for (int e = 0; e < 16; ++e) {
    if (fabsf(v[e]) < TAU) {
      int slot = atomicAdd(&nFix, 1);
      if (slot < 96) fixIdx[slot] = (t << 4) + e;
    }
  }
  __syncthreads();
  const int nf = min(nFix, 96);
  unsigned fixmask = 0;
  for (int i = 0; i < nf; ++i) {
    const int col = fixIdx[i];
    double s = 0.0;
    const float* wr = W + (size_t)col * K;
    if (Af) {
      const float* ar = Af + (size_t)row * K;
      for (int k = t; k < K; k += 256) s += (double)ar[k] * (double)wr[k];
    } else {
      const _Float16* ah = Ahi + (size_t)row * K;
      const _Float16* al = Alo + (size_t)row * K;
      for (int k = t; k < K; k += 256)
        s += ((double)(float)ah[k] + (double)(float)al[k] * (1.0 / 2048.0)) * (double)wr[k];
    }
#pragma unroll
    for (int off = 32; off; off >>= 1) s += __shfl_xor(s, off);
    if ((t & 63) == 0) sRed[t >> 6] = s;
    __syncthreads();
    if (t == 0)
      sVal = (float)(sRed[0] + sRed[1] + sRed[2] + sRed[3] + (double)bias[col]);
    __syncthreads();
    if ((col >> 4) == t) { v[col & 15] = sVal; fixmask |= 1u << (col & 15); }
  }
  __syncthreads();

  int fp = 0x7fffffff, fn = 0x7fffffff;
#pragma unroll
  for (int j = 0; j < 4; ++j) {
    bool ap = (v[j*4+0] > 0.f) & (v[j*4+1] > 0.f) & (v[j*4+2] > 0.f) & (v[j*4+3] > 0.f);
    bool an = (v[j*4+0] < 0.f) & (v[j*4+1] < 0.f) & (v[j*4+2] < 0.f) & (v[j*4+3] < 0.f);
    int g = (t << 2) + j;
    if (ap && g < fp) fp = g;
    if (an && g < fn) fn = g;
  }
#pragma unroll
  for (int off = 32; off; off >>= 1) {
    fp = min(fp, __shfl_xor(fp, off));
    fn = min(fn, __shfl_xor(fn, off));
  }
  if ((t & 63) == 0) { sPos[t >> 6] = fp; sNeg[t >> 6] = fn; }
  __syncthreads();
  fp = min(min(sPos[0], sPos[1]), min(sPos[2], sPos[3]));
  fn = min(min(sNeg[0], sNeg[1]), min(sNeg[2], sNeg[3]));
  const int act   = (fp == 0x7fffffff) ? -1 : fp;
  const int inact = (fn == 0x7fffffff) ? -1 : fn;

  unsigned chg = fixmask;
#pragma unroll
  for (int j = 0; j < 4; ++j) {
    int g = (t << 2) + j;
    if (g == act) {
      v[j*4+0] *= 2.f; v[j*4+1] *= 2.f; v[j*4+2] *= 2.f; v[j*4+3] *= 2.f;
      chg |= 0xFu << (j * 4);
    } else if (g == inact) {
      v[j*4+0] = v[j*4+1] = v[j*4+2] = v[j*4+3] = 0.f;
      chg |= 0xFu << (j * 4);
    }
  }
  while (chg) {
    int e = __ffs(chg) - 1; chg &= chg - 1;
    float val = v[e];
    _Float16 hh = (_Float16)val;
    zh[(t << 4) + e] = hh;
    if (zl) zl[(t << 4) + e] = (_Float16)((val - (float)hh) * 2048.0f);
  }
}

extern "C" void kernel_launch(void* const* d_in, const int* in_sizes, int n_in,
                              void* d_out, int out_size, void* d_ws, size_t ws_size,
                              hipStream_t stream) {
  const float* x  = (const float*)d_in[0];
  const float* W1 = (const float*)d_in[1];
  const float* b1 = (const float*)d_in[2];
  const float* W2 = (const float*)d_in[3];
  const float* b2 = (const float*)d_in[4];
  const float* W3 = (const float*)d_in[5];
  const float* b3 = (const float*)d_in[6];
  float* out = (float*)d_out;

  const int M = 8192, H = 4096, DIN = 1024, DOUT = 1024;

  // Scratch: 256 MiB, time-sliced aliasing (r5-proven layout; W2lo now unused).
  char* w = (char*)d_ws;
  _Float16* Z1hi = (_Float16*)(w + 0);
  _Float16* Z1lo = (_Float16*)(w + ((size_t)64 << 20));
  _Float16* Z2hi = (_Float16*)(w + ((size_t)128 << 20));
  _Float16* W2hi = (_Float16*)(w + ((size_t)192 << 20));
  // aliases (dead before their region's long-term owner is written)
  _Float16* xhi  = (_Float16*)(w + ((size_t)128 << 20));
  _Float16* xlo  = (_Float16*)(w + ((size_t)144 << 20));
  _Float16* W1hi = (_Float16*)(w + ((size_t)160 << 20));
  _Float16* W1lo = (_Float16*)(w + ((size_t)168 << 20));
  _Float16* W3hi = (_Float16*)(w + ((size_t)64 << 20));   // after sda_fix(L2)

  auto split = [&](const float* src, _Float16* hi, _Float16* lo, size_t n) {
    size_t n4 = n >> 2;
    int grid = (int)((n4 + 255) / 256);
    if (grid > 2048) grid = 2048;
    split_kernel<<<grid, 256, 0, stream>>>(src, hi, lo, n4);
  };
  split(x,  xhi,  xlo,  (size_t)M * DIN);
  split(W1, W1hi, W1lo, (size_t)H * DIN);
  split(W2, W2hi, (_Float16*)nullptr, (size_t)H * H);   // hi-only for L2

  // L1: Z1 = x @ W1^T + b1   (K=1024) — split-f16 precise, hi/lo out
  gemm_tri<0><<<dim3(H / BN, M / BM), dim3(1024), 0, stream>>>(
      xhi, xlo, W1hi, W1lo, b1, Z1hi, Z1lo, (float*)nullptr, M, H, DIN);
  sda_fix<<<M, 256, 0, stream>>>(Z1hi, Z1lo, x, (const _Float16*)nullptr,
                                 (const _Float16*)nullptr, W1, b1, H, DIN, 1e-4f);
  // L2: Z2 = Z1 @ W2^T + b2  (K=4096) — hi-only f16 256x256 kernel; masks fixed
  // downstream by fp64 recheck with TAU=5e-3 against precise Z1 (hi+lo)
  gemm_sq<<<dim3(H / 256, M / 256), dim3(1024), 0, stream>>>(
      Z1hi, W2hi, b2, Z2hi, M, H, H);
  sda_fix<<<M, 256, 0, stream>>>(Z2hi, (_Float16*)nullptr, (const float*)nullptr,
                                 Z1hi, Z1lo, W2, b2, H, H, 5e-3f);
  // L3: out = Z2 @ W3^T + b3 (N=1024) — hi-only
  split(W3, W3hi, (_Float16*)nullptr, (size_t)DOUT * H);
  gemm_tri<2><<<dim3(DOUT / BN, M / BM), dim3(1024), 0, stream>>>(
      Z2hi, (const _Float16*)nullptr, W3hi, (const _Float16*)nullptr, b3,
      (_Float16*)nullptr, (_Float16*)nullptr, out, M, DOUT, H);
}

// Round 10
// 634.409 us; speedup vs baseline: 3.8665x; 3.8665x over previous
//
#include <hip/hip_runtime.h>
#include <stdint.h>

using half8 = __attribute__((ext_vector_type(8))) _Float16;
using half4 = __attribute__((ext_vector_type(4))) _Float16;
using f32x4 = __attribute__((ext_vector_type(4))) float;

#define BM 256
#define BN 128
#define BK 32

// Bank-conflict-free layout: granule (row, k8) at byte row*64 + (k8 ^ ((row>>1)&3))*16.
// Read side uses swz() (16-row column reads -> 2-way aliasing = free);
// GLD staging realizes it via pre-swizzled global source addresses
// (LDS dest must be linear: wave-uniform base + lane*16).
__device__ __forceinline__ int swz(int row, int kb) {
  return (row << 6) + ((((kb >> 4) ^ ((row >> 1) & 3)) << 4) | (kb & 15));
}

#define GLD(src, dst)                                                          \
  __builtin_amdgcn_global_load_lds(                                            \
      (const __attribute__((address_space(1))) void*)(src),                    \
      (__attribute__((address_space(3))) void*)(dst), 16, 0, 0)

// ---------------- L1/L3 kernel (r7-proven): tri-buffer counted-vmcnt --------
// MODE 0: hi/lo inputs -> Chi+Clo (split-f16 precise, 3 MFMA/frag).
// MODE 2: hi-only inputs -> f32 C.
template <int MODE>
__global__ __launch_bounds__(1024, 4)
void gemm_tri(const _Float16* __restrict__ Ahi, const _Float16* __restrict__ Alo,
              const _Float16* __restrict__ Bhi, const _Float16* __restrict__ Blo,
              const float* __restrict__ bias,
              _Float16* __restrict__ Chi, _Float16* __restrict__ Clo,
              float* __restrict__ Cf, int M, int N, int K) {
  constexpr bool LO = (MODE < 2);
  constexpr int AHI = 0;
  constexpr int ALO = 16384;
  constexpr int BHI = LO ? 32768 : 16384;
  constexpr int BLO = 40960;
  constexpr int STG = LO ? 49152 : 24576;
  __shared__ char lds[3 * STG];

  const int tid = threadIdx.x;
  const int m0 = blockIdx.y * BM;
  const int n0 = blockIdx.x * BN;
  const int wave = tid >> 6, lane = tid & 63;
  const int wm = wave >> 1, wn = wave & 1;   // 8x2 wave grid; wave tile 32x64
  const int NK = K / BK;

  f32x4 acc_hi[2][4], acc_mid[2][4];
#pragma unroll
  for (int m = 0; m < 2; m++)
#pragma unroll
    for (int n = 0; n < 4; n++) { acc_hi[m][n] = (f32x4)0.0f; acc_mid[m][n] = (f32x4)0.0f; }

  const int srow = tid >> 2;                  // 0..255 (A rows)
  const int kx = (tid & 3) ^ ((srow >> 1) & 3);
  const size_t aoff = (size_t)(m0 + srow) * K + kx * 8;
  const int brow = (tid & 511) >> 2;          // 0..127 (B rows)
  const size_t boff = (size_t)(n0 + brow) * K + kx * 8;

  auto STAGE = [&](int buf, int ks) {
    char* sb = lds + buf * STG;
    const size_t ko = (size_t)ks * BK;
    GLD(Ahi + aoff + ko, sb + AHI + (wave << 10));
    if constexpr (LO) {
      GLD(Alo + aoff + ko, sb + ALO + (wave << 10));
      if (wave < 8) GLD(Bhi + boff + ko, sb + BHI + (wave << 10));
      else          GLD(Blo + boff + ko, sb + BLO + ((wave - 8) << 10));
    } else {
      if (wave < 8) GLD(Bhi + boff + ko, sb + BHI + (wave << 10));
    }
  };

  auto COMPUTE = [&](int buf) {
    char* base = lds + buf * STG;
    const int kb = (lane >> 4) << 4;
    const int rl = lane & 15;
    half8 ah[2], al[2], bh[4], bl[4];
#pragma unroll
    for (int mi = 0; mi < 2; mi++) {
      int off = swz(wm * 32 + mi * 16 + rl, kb);
      ah[mi] = *(half8*)(base + AHI + off);
      if constexpr (LO) al[mi] = *(half8*)(base + ALO + off);
    }
#pragma unroll
    for (int ni = 0; ni < 4; ni++) {
      int off = swz(wn * 64 + ni * 16 + rl, kb);
      bh[ni] = *(half8*)(base + BHI + off);
      if constexpr (LO) bl[ni] = *(half8*)(base + BLO + off);
    }
    __builtin_amdgcn_s_setprio(1);
#pragma unroll
    for (int mi = 0; mi < 2; mi++)
#pragma unroll
      for (int ni = 0; ni < 4; ni++) {
        acc_hi[mi][ni] = __builtin_amdgcn_mfma_f32_16x16x32_f16(ah[mi], bh[ni], acc_hi[mi][ni], 0, 0, 0);
        if constexpr (LO) {
          acc_mid[mi][ni] = __builtin_amdgcn_mfma_f32_16x16x32_f16(ah[mi], bl[ni], acc_mid[mi][ni], 0, 0, 0);
          acc_mid[mi][ni] = __builtin_amdgcn_mfma_f32_16x16x32_f16(al[mi], bh[ni], acc_mid[mi][ni], 0, 0, 0);
        }
      }
    __builtin_amdgcn_s_setprio(0);
  };

  STAGE(0, 0);
  STAGE(1, 1);
  int cur = 0;
  for (int ks = 0; ks < NK; ++ks) {
    if (ks + 1 < NK) {
      if constexpr (LO) {
        asm volatile("s_waitcnt vmcnt(3)" ::: "memory");
      } else {
        if (wave < 8) asm volatile("s_waitcnt vmcnt(2)" ::: "memory");
        else          asm volatile("s_waitcnt vmcnt(1)" ::: "memory");
      }
    } else {
      asm volatile("s_waitcnt vmcnt(0)" ::: "memory");
    }
    __builtin_amdgcn_s_barrier();
    if (ks + 2 < NK) {
      int nbuf = cur + 2; if (nbuf >= 3) nbuf -= 3;
      STAGE(nbuf, ks + 2);
    }
    COMPUTE(cur);
    if (++cur == 3) cur = 0;
  }

  const int col_l = lane & 15, rgrp = lane >> 4;
#pragma unroll
  for (int ni = 0; ni < 4; ni++) {
    int col = n0 + wn * 64 + ni * 16 + col_l;
    float bv = bias[col];
#pragma unroll
    for (int mi = 0; mi < 2; mi++) {
      int rowb = m0 + wm * 32 + mi * 16 + rgrp * 4;
#pragma unroll
      for (int i = 0; i < 4; i++) {
        size_t idx = (size_t)(rowb + i) * N + col;
        if constexpr (MODE == 2) {
          Cf[idx] = acc_hi[mi][ni][i] + bv;
        } else {
          float c = acc_hi[mi][ni][i] + acc_mid[mi][ni][i] * (1.0f / 2048.0f) + bv;
          _Float16 hh = (_Float16)c;
          Chi[idx] = hh;
          if constexpr (MODE == 0) Clo[idx] = (_Float16)((c - (float)hh) * 2048.0f);
        }
      }
    }
  }
}

// ---------------- L2 kernel: hi-only f16, 256x256 tile, 64x64 wave tiles ----
#define SQ_STG 32768

__global__ __launch_bounds__(1024, 4)
void gemm_sq(const _Float16* __restrict__ Ahi, const _Float16* __restrict__ Bhi,
             const float* __restrict__ bias, _Float16* __restrict__ Chi,
             int M, int N, int K) {
  __shared__ char lds[3 * SQ_STG];
  const int tid = threadIdx.x;
  const int m0 = blockIdx.y * 256;
  const int n0 = blockIdx.x * 256;
  const int wave = tid >> 6, lane = tid & 63;
  const int wm = wave >> 2, wn = wave & 3;   // 4x4 wave grid; wave tile 64x64
  const int NK = K / BK;

  f32x4 acc[4][4];
#pragma unroll
  for (int m = 0; m < 4; m++)
#pragma unroll
    for (int n = 0; n < 4; n++) acc[m][n] = (f32x4)0.0f;

  const int srow = tid >> 2;                  // 0..255
  const int kx = (tid & 3) ^ ((srow >> 1) & 3);
  const size_t aoff = (size_t)(m0 + srow) * K + kx * 8;
  const size_t boff = (size_t)(n0 + srow) * K + kx * 8;

  const int kb = (lane >> 4) << 4;
  const int rl = lane & 15;
  int aswz[4], bswz[4];
#pragma unroll
  for (int i = 0; i < 4; i++) {
    aswz[i] = swz(wm * 64 + i * 16 + rl, kb);
    bswz[i] = 16384 + swz(wn * 64 + i * 16 + rl, kb);
  }

  auto STAGE = [&](int buf, int ks) {
    char* sb = lds + buf * SQ_STG + (wave << 10);
    const size_t ko = (size_t)ks * BK;
    GLD(Ahi + aoff + ko, sb);
    GLD(Bhi + boff + ko, sb + 16384);
  };

  auto COMPUTE = [&](int buf) {
    char* base = lds + buf * SQ_STG;
    half8 ah[4], bh[4];
#pragma unroll
    for (int i = 0; i < 4; i++) {
      ah[i] = *(half8*)(base + aswz[i]);
      bh[i] = *(half8*)(base + bswz[i]);
    }
    __builtin_amdgcn_s_setprio(1);
#pragma unroll
    for (int mi = 0; mi < 4; mi++)
#pragma unroll
      for (int ni = 0; ni < 4; ni++)
        acc[mi][ni] = __builtin_amdgcn_mfma_f32_16x16x32_f16(ah[mi], bh[ni], acc[mi][ni], 0, 0, 0);
    __builtin_amdgcn_s_setprio(0);
  };

  STAGE(0, 0);
  STAGE(1, 1);
  int cur = 0;
  for (int ks = 0; ks < NK; ++ks) {
    if (ks + 1 < NK) asm volatile("s_waitcnt vmcnt(2)" ::: "memory");
    else             asm volatile("s_waitcnt vmcnt(0)" ::: "memory");
    __builtin_amdgcn_s_barrier();
    if (ks + 2 < NK) {
      int nbuf = cur + 2; if (nbuf >= 3) nbuf -= 3;
      STAGE(nbuf, ks + 2);
    }
    COMPUTE(cur);
    if (++cur == 3) cur = 0;
  }

  const int col_l = lane & 15, rgrp = lane >> 4;
#pragma unroll
  for (int ni = 0; ni < 4; ni++) {
    int col = n0 + wn * 64 + ni * 16 + col_l;
    float bv = bias[col];
#pragma unroll
    for (int mi = 0; mi < 4; mi++) {
      int rowb = m0 + wm * 64 + mi * 16 + rgrp * 4;
#pragma unroll
      for (int i = 0; i < 4; i++)
        Chi[(size_t)(rowb + i) * N + col] = (_Float16)(acc[mi][ni][i] + bv);
    }
  }
}

// Split f32 -> (hi f16, lo f16 scaled by 2048). Xlo may be null (hi-only).
__global__ __launch_bounds__(256)
void split_kernel(const float* __restrict__ X, _Float16* __restrict__ Xhi,
                  _Float16* __restrict__ Xlo, size_t n4) {
  size_t i = (size_t)blockIdx.x * 256 + threadIdx.x;
  const size_t stride = (size_t)gridDim.x * 256;
  for (; i < n4; i += stride) {
    float4 q = ((const float4*)X)[i];
    float a[4] = {q.x, q.y, q.z, q.w};
    half4 h, l;
#pragma unroll
    for (int j = 0; j < 4; ++j) {
      _Float16 hh = (_Float16)a[j];
      h[j] = hh;
      l[j] = (_Float16)((a[j] - (float)hh) * 2048.0f);
    }
    ((half4*)Xhi)[i] = h;
    if (Xlo) ((half4*)Xlo)[i] = l;
  }
}

// One block per row of Z. MASK-RELEVANCE-FILTERED fp64 recheck:
// a borderline elem (|v|<TAU) is rechecked ONLY if its group could change the
// first all-pos / all-neg selection:
//   pos-relevant: group all > -TAU (possibly all-pos), not all > TAU (not
//                 certain), and group idx <= first certainly-all-pos group.
//   neg-relevant: symmetric.
// Groups past the first certain group can never win argmax; non-possible
// groups contain a certainly-wrong-sign elem under any resolution -> filter
// is exact for mask computation. Non-relevant borderline values keep the
// GEMM value (error <= ~1.6e-3, harmless vs 0.0216 threshold).
__global__ __launch_bounds__(256)
void sda_fix(_Float16* __restrict__ Zhi, _Float16* __restrict__ Zlo,
             const float* __restrict__ Af,
             const _Float16* __restrict__ Ahi, const _Float16* __restrict__ Alo,
             const float* __restrict__ W, const float* __restrict__ bias,
             int H, int K, float TAU) {
  __shared__ int sPos[4], sNeg[4];
  __shared__ int nFix;
  __shared__ int fixIdx[96];
  __shared__ double sRed[4];
  __shared__ float sVal;
  const int row = blockIdx.x;
  _Float16* zh = Zhi + (size_t)row * H;
  _Float16* zl = Zlo ? Zlo + (size_t)row * H : nullptr;
  const int t = threadIdx.x;

  if (t == 0) nFix = 0;
  __syncthreads();

  float v[16];
  {
    half8 a0 = ((const half8*)zh)[t * 2], a1 = ((const half8*)zh)[t * 2 + 1];
    if (zl) {
      half8 b0 = ((const half8*)zl)[t * 2], b1 = ((const half8*)zl)[t * 2 + 1];
#pragma unroll
      for (int e = 0; e < 8; ++e) {
        v[e]     = (float)a0[e] + (float)b0[e] * (1.0f / 2048.0f);
        v[8 + e] = (float)a1[e] + (float)b1[e] * (1.0f / 2048.0f);
      }
    } else {
#pragma unroll
      for (int e = 0; e < 8; ++e) { v[e] = (float)a0[e]; v[8 + e] = (float)a1[e]; }
    }
  }

  // ---- group classification: certain / possible all-pos / all-neg ----
  bool cposa[4], pposa[4], cnega[4], pnega[4];
  int firstCpos = 0x7fffffff, firstCneg = 0x7fffffff;
#pragma unroll
  for (int j = 0; j < 4; ++j) {
    float g0 = v[j*4], g1 = v[j*4+1], g2 = v[j*4+2], g3 = v[j*4+3];
    cposa[j] = (g0 >  TAU) & (g1 >  TAU) & (g2 >  TAU) & (g3 >  TAU);
    pposa[j] = (g0 > -TAU) & (g1 > -TAU) & (g2 > -TAU) & (g3 > -TAU);
    cnega[j] = (g0 < -TAU) & (g1 < -TAU) & (g2 < -TAU) & (g3 < -TAU);
    pnega[j] = (g0 <  TAU) & (g1 <  TAU) & (g2 <  TAU) & (g3 <  TAU);
    int gi = (t << 2) + j;
    if (cposa[j] && gi < firstCpos) firstCpos = gi;
    if (cnega[j] && gi < firstCneg) firstCneg = gi;
  }
#pragma unroll
  for (int off = 32; off; off >>= 1) {
    firstCpos = min(firstCpos, __shfl_xor(firstCpos, off));
    firstCneg = min(firstCneg, __shfl_xor(firstCneg, off));
  }
  if ((t & 63) == 0) { sPos[t >> 6] = firstCpos; sNeg[t >> 6] = firstCneg; }
  __syncthreads();
  firstCpos = min(min(sPos[0], sPos[1]), min(sPos[2], sPos[3]));
  firstCneg = min(min(sNeg[0], sNeg[1]), min(sNeg[2], sNeg[3]));
  __syncthreads();   // sPos/sNeg reused below

  // ---- flag only mask-relevant borderline elements ----
#pragma unroll
  for (int j = 0; j < 4; ++j) {
    int gi = (t << 2) + j;
    bool qual = (pposa[j] && !cposa[j] && gi <= firstCpos) ||
                (pnega[j] && !cnega[j] && gi <= firstCneg);
    if (qual) {
#pragma unroll
      for (int e = 0; e < 4; ++e) {
        if (fabsf(v[j*4+e]) < TAU) {
          int slot = atomicAdd(&nFix, 1);
          if (slot < 96) fixIdx[slot] = gi * 4 + e;
        }
      }
    }
  }
  __syncthreads();
  const int nf = min(nFix, 96);
  unsigned fixmask = 0;
  for (int i = 0; i < nf; ++i) {
    const int col = fixIdx[i];
    double s = 0.0;
    const float* wr = W + (size_t)col * K;
    if (Af) {
      const float* ar = Af + (size_t)row * K;
      for (int k = t; k < K; k += 256) s += (double)ar[k] * (double)wr[k];
    } else {
      const _Float16* ah = Ahi + (size_t)row * K;
      const _Float16* al = Alo + (size_t)row * K;
      for (int k = t; k < K; k += 256)
        s += ((double)(float)ah[k] + (double)(float)al[k] * (1.0 / 2048.0)) * (double)wr[k];
    }
#pragma unroll
    for (int off = 32; off; off >>= 1) s += __shfl_xor(s, off);
    if ((t & 63) == 0) sRed[t >> 6] = s;
    __syncthreads();
    if (t == 0)
      sVal = (float)(sRed[0] + sRed[1] + sRed[2] + sRed[3] + (double)bias[col]);
    __syncthreads();
    if ((col >> 4) == t) { v[col & 15] = sVal; fixmask |= 1u << (col & 15); }
    __syncthreads();
  }

  // ---- final masks on corrected values ----
  int fp = 0x7fffffff, fn = 0x7fffffff;
#pragma unroll
  for (int j = 0; j < 4; ++j) {
    bool ap = (v[j*4+0] > 0.f) & (v[j*4+1] > 0.f) & (v[j*4+2] > 0.f) & (v[j*4+3] > 0.f);
    bool an = (v[j*4+0] < 0.f) & (v[j*4+1] < 0.f) & (v[j*4+2] < 0.f) & (v[j*4+3] < 0.f);
    int g = (t << 2) + j;
    if (ap && g < fp) fp = g;
    if (an && g < fn) fn = g;
  }
#pragma unroll
  for (int off = 32; off; off >>= 1) {
    fp = min(fp, __shfl_xor(fp, off));
    fn = min(fn, __shfl_xor(fn, off));
  }
  if ((t & 63) == 0) { sPos[t >> 6] = fp; sNeg[t >> 6] = fn; }
  __syncthreads();
  fp = min(min(sPos[0], sPos[1]), min(sPos[2], sPos[3]));
  fn = min(min(sNeg[0], sNeg[1]), min(sNeg[2], sNeg[3]));
  const int act   = (fp == 0x7fffffff) ? -1 : fp;
  const int inact = (fn == 0x7fffffff) ? -1 : fn;

  unsigned chg = fixmask;
#pragma unroll
  for (int j = 0; j < 4; ++j) {
    int g = (t << 2) + j;
    if (g == act) {
      v[j*4+0] *= 2.f; v[j*4+1] *= 2.f; v[j*4+2] *= 2.f; v[j*4+3] *= 2.f;
      chg |= 0xFu << (j * 4);
    } else if (g == inact) {
      v[j*4+0] = v[j*4+1] = v[j*4+2] = v[j*4+3] = 0.f;
      chg |= 0xFu << (j * 4);
    }
  }
  while (chg) {
    int e = __ffs(chg) - 1; chg &= chg - 1;
    float val = v[e];
    _Float16 hh = (_Float16)val;
    zh[(t << 4) + e] = hh;
    if (zl) zl[(t << 4) + e] = (_Float16)((val - (float)hh) * 2048.0f);
  }
}

extern "C" void kernel_launch(void* const* d_in, const int* in_sizes, int n_in,
                              void* d_out, int out_size, void* d_ws, size_t ws_size,
                              hipStream_t stream) {
  const float* x  = (const float*)d_in[0];
  const float* W1 = (const float*)d_in[1];
  const float* b1 = (const float*)d_in[2];
  const float* W2 = (const float*)d_in[3];
  const float* b2 = (const float*)d_in[4];
  const float* W3 = (const float*)d_in[5];
  const float* b3 = (const float*)d_in[6];
  float* out = (float*)d_out;

  const int M = 8192, H = 4096, DIN = 1024, DOUT = 1024;

  // Scratch: 256 MiB, time-sliced aliasing (r5-proven layout).
  char* w = (char*)d_ws;
  _Float16* Z1hi = (_Float16*)(w + 0);
  _Float16* Z1lo = (_Float16*)(w + ((size_t)64 << 20));
  _Float16* Z2hi = (_Float16*)(w + ((size_t)128 << 20));
  _Float16* W2hi = (_Float16*)(w + ((size_t)192 << 20));
  // aliases (dead before their region's long-term owner is written)
  _Float16* xhi  = (_Float16*)(w + ((size_t)128 << 20));
  _Float16* xlo  = (_Float16*)(w + ((size_t)144 << 20));
  _Float16* W1hi = (_Float16*)(w + ((size_t)160 << 20));
  _Float16* W1lo = (_Float16*)(w + ((size_t)168 << 20));
  _Float16* W3hi = (_Float16*)(w + ((size_t)64 << 20));   // after sda_fix(L2)

  auto split = [&](const float* src, _Float16* hi, _Float16* lo, size_t n) {
    size_t n4 = n >> 2;
    int grid = (int)((n4 + 255) / 256);
    if (grid > 2048) grid = 2048;
    split_kernel<<<grid, 256, 0, stream>>>(src, hi, lo, n4);
  };
  split(x,  xhi,  xlo,  (size_t)M * DIN);
  split(W1, W1hi, W1lo, (size_t)H * DIN);
  split(W2, W2hi, (_Float16*)nullptr, (size_t)H * H);   // hi-only for L2

  // L1: Z1 = x @ W1^T + b1   (K=1024) — split-f16 precise, hi/lo out
  gemm_tri<0><<<dim3(H / BN, M / BM), dim3(1024), 0, stream>>>(
      xhi, xlo, W1hi, W1lo, b1, Z1hi, Z1lo, (float*)nullptr, M, H, DIN);
  sda_fix<<<M, 256, 0, stream>>>(Z1hi, Z1lo, x, (const _Float16*)nullptr,
                                 (const _Float16*)nullptr, W1, b1, H, DIN, 1e-4f);
  // L2: Z2 = Z1 @ W2^T + b2  (K=4096) — hi-only f16 256x256 kernel; masks fixed
  // downstream by filtered fp64 recheck with TAU=5e-3 against precise Z1
  gemm_sq<<<dim3(H / 256, M / 256), dim3(1024), 0, stream>>>(
      Z1hi, W2hi, b2, Z2hi, M, H, H);
  sda_fix<<<M, 256, 0, stream>>>(Z2hi, (_Float16*)nullptr, (const float*)nullptr,
                                 Z1hi, Z1lo, W2, b2, H, H, 5e-3f);
  // L3: out = Z2 @ W3^T + b3 (N=1024) — hi-only
  split(W3, W3hi, (_Float16*)nullptr, (size_t)DOUT * H);
  gemm_tri<2><<<dim3(DOUT / BN, M / BM), dim3(1024), 0, stream>>>(
      Z2hi, (const _Float16*)nullptr, W3hi, (const _Float16*)nullptr, b3,
      (_Float16*)nullptr, (_Float16*)nullptr, out, M, DOUT, H);
}

// Round 11
// 613.899 us; speedup vs baseline: 3.9957x; 1.0334x over previous
//
#include <hip/hip_runtime.h>
#include <stdint.h>

using half8 = __attribute__((ext_vector_type(8))) _Float16;
using half4 = __attribute__((ext_vector_type(4))) _Float16;
using f32x4 = __attribute__((ext_vector_type(4))) float;

#define BM 256
#define BN 128
#define BK 32

// Bank-conflict-free layout: granule (row, k8) at byte row*64 + (k8 ^ ((row>>1)&3))*16.
// Read side uses swz() (16-row column reads -> 2-way aliasing = free);
// GLD staging realizes it via pre-swizzled global source addresses
// (LDS dest must be linear: wave-uniform base + lane*16).
__device__ __forceinline__ int swz(int row, int kb) {
  return (row << 6) + ((((kb >> 4) ^ ((row >> 1) & 3)) << 4) | (kb & 15));
}

// XCD-bijective block swizzle (requires gridDim.x % 8 == 0): XCD k owns a
// contiguous chunk of logical tile ids -> neighboring tiles share L2.
__device__ __forceinline__ int xcd_swz(int bid, int nwg) {
  int cpx = nwg >> 3;
  return (bid & 7) * cpx + (bid >> 3);
}

#define GLD(src, dst)                                                          \
  __builtin_amdgcn_global_load_lds(                                            \
      (const __attribute__((address_space(1))) void*)(src),                    \
      (__attribute__((address_space(3))) void*)(dst), 16, 0, 0)

// ---------------- L1/L3 kernel (r7-proven): tri-buffer counted-vmcnt --------
// MODE 0: hi/lo inputs -> Chi+Clo (split-f16 precise, 3 MFMA/frag).
// MODE 2: hi-only inputs -> f32 C.
template <int MODE>
__global__ __launch_bounds__(1024, 4)
void gemm_tri(const _Float16* __restrict__ Ahi, const _Float16* __restrict__ Alo,
              const _Float16* __restrict__ Bhi, const _Float16* __restrict__ Blo,
              const float* __restrict__ bias,
              _Float16* __restrict__ Chi, _Float16* __restrict__ Clo,
              float* __restrict__ Cf, int M, int N, int K, int nbx) {
  constexpr bool LO = (MODE < 2);
  constexpr int AHI = 0;
  constexpr int ALO = 16384;
  constexpr int BHI = LO ? 32768 : 16384;
  constexpr int BLO = 40960;
  constexpr int STG = LO ? 49152 : 24576;
  __shared__ char lds[3 * STG];

  const int tid = threadIdx.x;
  const int sid = xcd_swz(blockIdx.x, gridDim.x);
  const int m0 = (sid / nbx) * BM;
  const int n0 = (sid % nbx) * BN;
  const int wave = tid >> 6, lane = tid & 63;
  const int wm = wave >> 1, wn = wave & 1;   // 8x2 wave grid; wave tile 32x64
  const int NK = K / BK;

  f32x4 acc_hi[2][4], acc_mid[2][4];
#pragma unroll
  for (int m = 0; m < 2; m++)
#pragma unroll
    for (int n = 0; n < 4; n++) { acc_hi[m][n] = (f32x4)0.0f; acc_mid[m][n] = (f32x4)0.0f; }

  const int srow = tid >> 2;                  // 0..255 (A rows)
  const int kx = (tid & 3) ^ ((srow >> 1) & 3);
  const size_t aoff = (size_t)(m0 + srow) * K + kx * 8;
  const int brow = (tid & 511) >> 2;          // 0..127 (B rows)
  const size_t boff = (size_t)(n0 + brow) * K + kx * 8;

  auto STAGE = [&](int buf, int ks) {
    char* sb = lds + buf * STG;
    const size_t ko = (size_t)ks * BK;
    GLD(Ahi + aoff + ko, sb + AHI + (wave << 10));
    if constexpr (LO) {
      GLD(Alo + aoff + ko, sb + ALO + (wave << 10));
      if (wave < 8) GLD(Bhi + boff + ko, sb + BHI + (wave << 10));
      else          GLD(Blo + boff + ko, sb + BLO + ((wave - 8) << 10));
    } else {
      if (wave < 8) GLD(Bhi + boff + ko, sb + BHI + (wave << 10));
    }
  };

  auto COMPUTE = [&](int buf) {
    char* base = lds + buf * STG;
    const int kb = (lane >> 4) << 4;
    const int rl = lane & 15;
    half8 ah[2], al[2], bh[4], bl[4];
#pragma unroll
    for (int mi = 0; mi < 2; mi++) {
      int off = swz(wm * 32 + mi * 16 + rl, kb);
      ah[mi] = *(half8*)(base + AHI + off);
      if constexpr (LO) al[mi] = *(half8*)(base + ALO + off);
    }
#pragma unroll
    for (int ni = 0; ni < 4; ni++) {
      int off = swz(wn * 64 + ni * 16 + rl, kb);
      bh[ni] = *(half8*)(base + BHI + off);
      if constexpr (LO) bl[ni] = *(half8*)(base + BLO + off);
    }
    __builtin_amdgcn_s_setprio(1);
#pragma unroll
    for (int mi = 0; mi < 2; mi++)
#pragma unroll
      for (int ni = 0; ni < 4; ni++) {
        acc_hi[mi][ni] = __builtin_amdgcn_mfma_f32_16x16x32_f16(ah[mi], bh[ni], acc_hi[mi][ni], 0, 0, 0);
        if constexpr (LO) {
          acc_mid[mi][ni] = __builtin_amdgcn_mfma_f32_16x16x32_f16(ah[mi], bl[ni], acc_mid[mi][ni], 0, 0, 0);
          acc_mid[mi][ni] = __builtin_amdgcn_mfma_f32_16x16x32_f16(al[mi], bh[ni], acc_mid[mi][ni], 0, 0, 0);
        }
      }
    __builtin_amdgcn_s_setprio(0);
  };

  STAGE(0, 0);
  STAGE(1, 1);
  int cur = 0;
  for (int ks = 0; ks < NK; ++ks) {
    if (ks + 1 < NK) {
      if constexpr (LO) {
        asm volatile("s_waitcnt vmcnt(3)" ::: "memory");
      } else {
        if (wave < 8) asm volatile("s_waitcnt vmcnt(2)" ::: "memory");
        else          asm volatile("s_waitcnt vmcnt(1)" ::: "memory");
      }
    } else {
      asm volatile("s_waitcnt vmcnt(0)" ::: "memory");
    }
    __builtin_amdgcn_s_barrier();
    if (ks + 2 < NK) {
      int nbuf = cur + 2; if (nbuf >= 3) nbuf -= 3;
      STAGE(nbuf, ks + 2);
    }
    COMPUTE(cur);
    if (++cur == 3) cur = 0;
  }

  const int col_l = lane & 15, rgrp = lane >> 4;
#pragma unroll
  for (int ni = 0; ni < 4; ni++) {
    int col = n0 + wn * 64 + ni * 16 + col_l;
    float bv = bias[col];
#pragma unroll
    for (int mi = 0; mi < 2; mi++) {
      int rowb = m0 + wm * 32 + mi * 16 + rgrp * 4;
#pragma unroll
      for (int i = 0; i < 4; i++) {
        size_t idx = (size_t)(rowb + i) * N + col;
        if constexpr (MODE == 2) {
          Cf[idx] = acc_hi[mi][ni][i] + bv;
        } else {
          float c = acc_hi[mi][ni][i] + acc_mid[mi][ni][i] * (1.0f / 2048.0f) + bv;
          _Float16 hh = (_Float16)c;
          Chi[idx] = hh;
          if constexpr (MODE == 0) Clo[idx] = (_Float16)((c - (float)hh) * 2048.0f);
        }
      }
    }
  }
}

// ---------------- L2 kernel: hi-only f16, 256x256 tile, BK=64 EPOCHS --------
// Two K-steps per barrier: {vmcnt(0); barrier; stage-half0(next);
// compute-half0; stage-half1(next); compute-half1}. Double buffer 2x64KB.
// Hazards: own-vmcnt + barrier publish all of buf's stages (issued last
// epoch); post-barrier stages target buf^1, read only next epoch (WAR-safe
// via barrier — a wave passes it only after consuming its epoch-e-1 reads).
// MFMA order per accumulator identical to the per-step version.
#define SQ_BUF 65536

__global__ __launch_bounds__(1024, 4)
void gemm_sq(const _Float16* __restrict__ Ahi, const _Float16* __restrict__ Bhi,
             const float* __restrict__ bias, _Float16* __restrict__ Chi,
             int M, int N, int K, int nbx) {
  __shared__ char lds[2 * SQ_BUF];
  const int tid = threadIdx.x;
  const int sid = xcd_swz(blockIdx.x, gridDim.x);
  const int m0 = (sid / nbx) * 256;
  const int n0 = (sid % nbx) * 256;
  const int wave = tid >> 6, lane = tid & 63;
  const int wm = wave >> 2, wn = wave & 3;   // 4x4 wave grid; wave tile 64x64
  const int NE = K / 64;                     // epochs of 2 K-steps

  f32x4 acc[4][4];
#pragma unroll
  for (int m = 0; m < 4; m++)
#pragma unroll
    for (int n = 0; n < 4; n++) acc[m][n] = (f32x4)0.0f;

  const int srow = tid >> 2;                  // 0..255
  const int kx = (tid & 3) ^ ((srow >> 1) & 3);
  const size_t aoff = (size_t)(m0 + srow) * K + kx * 8;
  const size_t boff = (size_t)(n0 + srow) * K + kx * 8;

  const int kb = (lane >> 4) << 4;
  const int rl = lane & 15;
  int aswz[4], bswz[4];
#pragma unroll
  for (int i = 0; i < 4; i++) {
    aswz[i] = swz(wm * 64 + i * 16 + rl, kb);
    bswz[i] = 16384 + swz(wn * 64 + i * 16 + rl, kb);
  }

  // half h of buffer b holds K-step (2*epoch + h); 32KB per half (A 16K, B 16K)
  auto STAGE_H = [&](int buf, int half, int ks) {
    char* sb = lds + buf * SQ_BUF + half * 32768 + (wave << 10);
    const size_t ko = (size_t)ks * BK;
    GLD(Ahi + aoff + ko, sb);
    GLD(Bhi + boff + ko, sb + 16384);
  };

  auto COMPUTE_H = [&](int buf, int half) {
    char* base = lds + buf * SQ_BUF + half * 32768;
    half8 ah[4], bh[4];
#pragma unroll
    for (int i = 0; i < 4; i++) {
      ah[i] = *(half8*)(base + aswz[i]);
      bh[i] = *(half8*)(base + bswz[i]);
    }
    __builtin_amdgcn_s_setprio(1);
#pragma unroll
    for (int mi = 0; mi < 4; mi++)
#pragma unroll
      for (int ni = 0; ni < 4; ni++)
        acc[mi][ni] = __builtin_amdgcn_mfma_f32_16x16x32_f16(ah[mi], bh[ni], acc[mi][ni], 0, 0, 0);
    __builtin_amdgcn_s_setprio(0);
  };

  STAGE_H(0, 0, 0);
  STAGE_H(0, 1, 1);
  int buf = 0;
  for (int e = 0; e < NE; ++e) {
    asm volatile("s_waitcnt vmcnt(0)" ::: "memory");
    __builtin_amdgcn_s_barrier();
    if (e + 1 < NE) STAGE_H(buf ^ 1, 0, 2 * e + 2);
    COMPUTE_H(buf, 0);
    if (e + 1 < NE) STAGE_H(buf ^ 1, 1, 2 * e + 3);
    COMPUTE_H(buf, 1);
    buf ^= 1;
  }

  const int col_l = lane & 15, rgrp = lane >> 4;
#pragma unroll
  for (int ni = 0; ni < 4; ni++) {
    int col = n0 + wn * 64 + ni * 16 + col_l;
    float bv = bias[col];
#pragma unroll
    for (int mi = 0; mi < 4; mi++) {
      int rowb = m0 + wm * 64 + mi * 16 + rgrp * 4;
#pragma unroll
      for (int i = 0; i < 4; i++)
        Chi[(size_t)(rowb + i) * N + col] = (_Float16)(acc[mi][ni][i] + bv);
    }
  }
}

// Fused split: 4 segments, f32 -> hi f16 (+ lo f16 x2048 where dst given).
__global__ __launch_bounds__(256)
void split4_kernel(const float* __restrict__ s0, _Float16* __restrict__ h0,
                   _Float16* __restrict__ l0, size_t n0,
                   const float* __restrict__ s1, _Float16* __restrict__ h1,
                   _Float16* __restrict__ l1, size_t n1,
                   const float* __restrict__ s2, _Float16* __restrict__ h2,
                   size_t n2,
                   const float* __restrict__ s3, _Float16* __restrict__ h3,
                   size_t n3) {
  const size_t tot = n0 + n1 + n2 + n3;   // in float4 units
  size_t i = (size_t)blockIdx.x * 256 + threadIdx.x;
  const size_t stride = (size_t)gridDim.x * 256;
  for (; i < tot; i += stride) {
    const float* src; _Float16* hi; _Float16* lo; size_t j = i;
    if (j < n0) { src = s0; hi = h0; lo = l0; }
    else if ((j -= n0) < n1) { src = s1; hi = h1; lo = l1; }
    else if ((j -= n1) < n2) { src = s2; hi = h2; lo = nullptr; }
    else { j -= n2; src = s3; hi = h3; lo = nullptr; }
    float4 q = ((const float4*)src)[j];
    float a[4] = {q.x, q.y, q.z, q.w};
    half4 h, l;
#pragma unroll
    for (int k = 0; k < 4; ++k) {
      _Float16 hh = (_Float16)a[k];
      h[k] = hh;
      l[k] = (_Float16)((a[k] - (float)hh) * 2048.0f);
    }
    ((half4*)hi)[j] = h;
    if (lo) ((half4*)lo)[j] = l;
  }
}

// One block per row of Z. MASK-RELEVANCE-FILTERED fp64 recheck (r10-proven):
// recheck a borderline elem only if its group could alter the first all-pos /
// all-neg selection. Exact for masks; non-relevant borderline values keep the
// GEMM value (err <= ~1.6e-3, harmless vs the 0.0216 threshold).
__global__ __launch_bounds__(256)
void sda_fix(_Float16* __restrict__ Zhi, _Float16* __restrict__ Zlo,
             const float* __restrict__ Af,
             const _Float16* __restrict__ Ahi, const _Float16* __restrict__ Alo,
             const float* __restrict__ W, const float* __restrict__ bias,
             int H, int K, float TAU) {
  __shared__ int sPos[4], sNeg[4];
  __shared__ int nFix;
  __shared__ int fixIdx[96];
  __shared__ double sRed[4];
  __shared__ float sVal;
  const int row = blockIdx.x;
  _Float16* zh = Zhi + (size_t)row * H;
  _Float16* zl = Zlo ? Zlo + (size_t)row * H : nullptr;
  const int t = threadIdx.x;

  if (t == 0) nFix = 0;
  __syncthreads();

  float v[16];
  {
    half8 a0 = ((const half8*)zh)[t * 2], a1 = ((const half8*)zh)[t * 2 + 1];
    if (zl) {
      half8 b0 = ((const half8*)zl)[t * 2], b1 = ((const half8*)zl)[t * 2 + 1];
#pragma unroll
      for (int e = 0; e < 8; ++e) {
        v[e]     = (float)a0[e] + (float)b0[e] * (1.0f / 2048.0f);
        v[8 + e] = (float)a1[e] + (float)b1[e] * (1.0f / 2048.0f);
      }
    } else {
#pragma unroll
      for (int e = 0; e < 8; ++e) { v[e] = (float)a0[e]; v[8 + e] = (float)a1[e]; }
    }
  }

  bool cposa[4], pposa[4], cnega[4], pnega[4];
  int firstCpos = 0x7fffffff, firstCneg = 0x7fffffff;
#pragma unroll
  for (int j = 0; j < 4; ++j) {
    float g0 = v[j*4], g1 = v[j*4+1], g2 = v[j*4+2], g3 = v[j*4+3];
    cposa[j] = (g0 >  TAU) & (g1 >  TAU) & (g2 >  TAU) & (g3 >  TAU);
    pposa[j] = (g0 > -TAU) & (g1 > -TAU) & (g2 > -TAU) & (g3 > -TAU);
    cnega[j] = (g0 < -TAU) & (g1 < -TAU) & (g2 < -TAU) & (g3 < -TAU);
    pnega[j] = (g0 <  TAU) & (g1 <  TAU) & (g2 <  TAU) & (g3 <  TAU);
    int gi = (t << 2) + j;
    if (cposa[j] && gi < firstCpos) firstCpos = gi;
    if (cnega[j] && gi < firstCneg) firstCneg = gi;
  }
#pragma unroll
  for (int off = 32; off; off >>= 1) {
    firstCpos = min(firstCpos, __shfl_xor(firstCpos, off));
    firstCneg = min(firstCneg, __shfl_xor(firstCneg, off));
  }
  if ((t & 63) == 0) { sPos[t >> 6] = firstCpos; sNeg[t >> 6] = firstCneg; }
  __syncthreads();
  firstCpos = min(min(sPos[0], sPos[1]), min(sPos[2], sPos[3]));
  firstCneg = min(min(sNeg[0], sNeg[1]), min(sNeg[2], sNeg[3]));
  __syncthreads();

#pragma unroll
  for (int j = 0; j < 4; ++j) {
    int gi = (t << 2) + j;
    bool qual = (pposa[j] && !cposa[j] && gi <= firstCpos) ||
                (pnega[j] && !cnega[j] && gi <= firstCneg);
    if (qual) {
#pragma unroll
      for (int e = 0; e < 4; ++e) {
        if (fabsf(v[j*4+e]) < TAU) {
          int slot = atomicAdd(&nFix, 1);
          if (slot < 96) fixIdx[slot] = gi * 4 + e;
        }
      }
    }
  }
  __syncthreads();
  const int nf = min(nFix, 96);
  unsigned fixmask = 0;
  for (int i = 0; i < nf; ++i) {
    const int col = fixIdx[i];
    double s = 0.0;
    const float* wr = W + (size_t)col * K;
    if (Af) {
      const float* ar = Af + (size_t)row * K;
      for (int k = t; k < K; k += 256) s += (double)ar[k] * (double)wr[k];
    } else {
      const _Float16* ah = Ahi + (size_t)row * K;
      const _Float16* al = Alo + (size_t)row * K;
      for (int k = t; k < K; k += 256)
        s += ((double)(float)ah[k] + (double)(float)al[k] * (1.0 / 2048.0)) * (double)wr[k];
    }
#pragma unroll
    for (int off = 32; off; off >>= 1) s += __shfl_xor(s, off);
    if ((t & 63) == 0) sRed[t >> 6] = s;
    __syncthreads();
    if (t == 0)
      sVal = (float)(sRed[0] + sRed[1] + sRed[2] + sRed[3] + (double)bias[col]);
    __syncthreads();
    if ((col >> 4) == t) { v[col & 15] = sVal; fixmask |= 1u << (col & 15); }
    __syncthreads();
  }

  int fp = 0x7fffffff, fn = 0x7fffffff;
#pragma unroll
  for (int j = 0; j < 4; ++j) {
    bool ap = (v[j*4+0] > 0.f) & (v[j*4+1] > 0.f) & (v[j*4+2] > 0.f) & (v[j*4+3] > 0.f);
    bool an = (v[j*4+0] < 0.f) & (v[j*4+1] < 0.f) & (v[j*4+2] < 0.f) & (v[j*4+3] < 0.f);
    int g = (t << 2) + j;
    if (ap && g < fp) fp = g;
    if (an && g < fn) fn = g;
  }
#pragma unroll
  for (int off = 32; off; off >>= 1) {
    fp = min(fp, __shfl_xor(fp, off));
    fn = min(fn, __shfl_xor(fn, off));
  }
  if ((t & 63) == 0) { sPos[t >> 6] = fp; sNeg[t >> 6] = fn; }
  __syncthreads();
  fp = min(min(sPos[0], sPos[1]), min(sPos[2], sPos[3]));
  fn = min(min(sNeg[0], sNeg[1]), min(sNeg[2], sNeg[3]));
  const int act   = (fp == 0x7fffffff) ? -1 : fp;
  const int inact = (fn == 0x7fffffff) ? -1 : fn;

  unsigned chg = fixmask;
#pragma unroll
  for (int j = 0; j < 4; ++j) {
    int g = (t << 2) + j;
    if (g == act) {
      v[j*4+0] *= 2.f; v[j*4+1] *= 2.f; v[j*4+2] *= 2.f; v[j*4+3] *= 2.f;
      chg |= 0xFu << (j * 4);
    } else if (g == inact) {
      v[j*4+0] = v[j*4+1] = v[j*4+2] = v[j*4+3] = 0.f;
      chg |= 0xFu << (j * 4);
    }
  }
  while (chg) {
    int e = __ffs(chg) - 1; chg &= chg - 1;
    float val = v[e];
    _Float16 hh = (_Float16)val;
    zh[(t << 4) + e] = hh;
    if (zl) zl[(t << 4) + e] = (_Float16)((val - (float)hh) * 2048.0f);
  }
}

extern "C" void kernel_launch(void* const* d_in, const int* in_sizes, int n_in,
                              void* d_out, int out_size, void* d_ws, size_t ws_size,
                              hipStream_t stream) {
  const float* x  = (const float*)d_in[0];
  const float* W1 = (const float*)d_in[1];
  const float* b1 = (const float*)d_in[2];
  const float* W2 = (const float*)d_in[3];
  const float* b2 = (const float*)d_in[4];
  const float* W3 = (const float*)d_in[5];
  const float* b3 = (const float*)d_in[6];
  float* out = (float*)d_out;

  const int M = 8192, H = 4096, DIN = 1024, DOUT = 1024;

  // Scratch: 256 MiB, time-sliced aliasing (r5-proven layout).
  char* w = (char*)d_ws;
  _Float16* Z1hi = (_Float16*)(w + 0);
  _Float16* Z1lo = (_Float16*)(w + ((size_t)64 << 20));
  _Float16* Z2hi = (_Float16*)(w + ((size_t)128 << 20));
  _Float16* W2hi = (_Float16*)(w + ((size_t)192 << 20));
  // aliases (dead before their region's long-term owner is written)
  _Float16* xhi  = (_Float16*)(w + ((size_t)128 << 20));
  _Float16* xlo  = (_Float16*)(w + ((size_t)144 << 20));
  _Float16* W1hi = (_Float16*)(w + ((size_t)160 << 20));
  _Float16* W1lo = (_Float16*)(w + ((size_t)168 << 20));
  _Float16* W3hi = (_Float16*)(w + ((size_t)224 << 20));   // spare region

  // One fused split pass: x (hi/lo), W1 (hi/lo), W2 (hi), W3 (hi).
  split4_kernel<<<2048, 256, 0, stream>>>(
      x,  xhi,  xlo,  (size_t)(M * DIN) >> 2,
      W1, W1hi, W1lo, (size_t)(H * DIN) >> 2,
      W2, W2hi,       (size_t)((size_t)H * H) >> 2,
      W3, W3hi,       (size_t)(DOUT * H) >> 2);

  // L1: Z1 = x @ W1^T + b1   (K=1024) — split-f16 precise, hi/lo out
  gemm_tri<0><<<dim3((H / BN) * (M / BM)), dim3(1024), 0, stream>>>(
      xhi, xlo, W1hi, W1lo, b1, Z1hi, Z1lo, (float*)nullptr, M, H, DIN, H / BN);
  sda_fix<<<M, 256, 0, stream>>>(Z1hi, Z1lo, x, (const _Float16*)nullptr,
                                 (const _Float16*)nullptr, W1, b1, H, DIN, 1e-4f);
  // L2: Z2 = Z1 @ W2^T + b2  (K=4096) — hi-only f16, 256x256, BK=64 epochs
  gemm_sq<<<dim3((H / 256) * (M / 256)), dim3(1024), 0, stream>>>(
      Z1hi, W2hi, b2, Z2hi, M, H, H, H / 256);
  sda_fix<<<M, 256, 0, stream>>>(Z2hi, (_Float16*)nullptr, (const float*)nullptr,
                                 Z1hi, Z1lo, W2, b2, H, H, 5e-3f);
  // L3: out = Z2 @ W3^T + b3 (N=1024) — hi-only
  gemm_tri<2><<<dim3((DOUT / BN) * (M / BM)), dim3(1024), 0, stream>>>(
      Z2hi, (const _Float16*)nullptr, W3hi, (const _Float16*)nullptr, b3,
      (_Float16*)nullptr, (_Float16*)nullptr, out, M, DOUT, H, DOUT / BN);
}